// Round 3
// baseline (137.854 us; speedup 1.0000x reference)
//
#include <hip/hip_runtime.h>

typedef __attribute__((ext_vector_type(8))) short short8;
typedef __attribute__((ext_vector_type(4))) float f32x4;

#define D 128
#define MARGIN 0.1f
#define BM 64      // rows per (1-wave) block
#define NCG 32     // column groups
#define MAXC 64    // max class size supported (n=8192, 512 classes -> ~16 +/- 4)

__device__ __forceinline__ unsigned short f32_to_bf16(float f) {
  unsigned int u = __float_as_uint(f);
  u += 0x7fffu + ((u >> 16) & 1u);
  return (unsigned short)(u >> 16);
}

// order-preserving float->uint key (no NaNs in this data)
__device__ __forceinline__ unsigned fkey(float f) {
  unsigned b = __float_as_uint(f);
  return b ^ (((unsigned)((int)b >> 31)) | 0x80000000u);
}
__device__ __forceinline__ float fdec(unsigned k) {
  unsigned b = k ^ ((k & 0x80000000u) ? 0x80000000u : 0xFFFFFFFFu);
  return __uint_as_float(b);
}

__global__ void k_convert(const float* __restrict__ x, unsigned short* __restrict__ xb, int total) {
  int i = (blockIdx.x * blockDim.x + threadIdx.x) * 4;
  if (i + 3 < total) {
    float4 v = *reinterpret_cast<const float4*>(x + i);
    ushort4 o;
    o.x = f32_to_bf16(v.x);
    o.y = f32_to_bf16(v.y);
    o.z = f32_to_bf16(v.z);
    o.w = f32_to_bf16(v.w);
    *reinterpret_cast<ushort4*>(xb + i) = o;
  }
}

// zero class counters + init row-max keys (ws is poisoned once; graph replays need re-init)
__global__ void k_zero(int* __restrict__ cls_cnt, unsigned* __restrict__ mn_u, int n) {
  int i = blockIdx.x * 256 + threadIdx.x;
  if (i < 512) cls_cnt[i] = 0;
  if (i < n) mn_u[i] = 0u;  // key 0 < key(-inf)=0x007FFFFF, below all real values
}

__global__ void k_fill(const int* __restrict__ tg, int* __restrict__ cls_cnt,
                       int* __restrict__ cls_idx, int n) {
  int i = blockIdx.x * 256 + threadIdx.x;
  if (i < n) {
    int c = tg[i];
    int s = atomicAdd(&cls_cnt[c], 1);
    if (s < MAXC) cls_idx[c * MAXC + s] = i;
  }
}

// Pass 1: per-row max over NEGATIVES only (same-class masked; diagonal is same-class).
// 1 wave per block, 64 rows x 256 cols, ping-pong B prefetch, atomicMax combine.
__launch_bounds__(64, 3)
__global__ void k_pass1(const unsigned short* __restrict__ xb, const int* __restrict__ tg,
                        unsigned* __restrict__ mn_u, int n) {
  const int lane = threadIdx.x;
  const int nstrips = n / BM;            // 128
  const int strip = blockIdx.x % nstrips;
  const int cgrp  = blockIdx.x / nstrips;
  const int r0 = strip * BM;
  const int NC = n / NCG;                // 256
  const int c0 = cgrp * NC;
  const int cg = lane & 15;
  const int agrp = lane >> 4;

  short8 a[4][4];
#pragma unroll
  for (int rt = 0; rt < 4; ++rt)
#pragma unroll
    for (int kk = 0; kk < 4; ++kk)
      a[rt][kk] = *reinterpret_cast<const short8*>(
          xb + (size_t)(r0 + rt * 16 + cg) * D + kk * 32 + agrp * 8);

  int trow[4][4];
  float mn[4][4];
#pragma unroll
  for (int rt = 0; rt < 4; ++rt)
#pragma unroll
    for (int reg = 0; reg < 4; ++reg) {
      trow[rt][reg] = tg[r0 + rt * 16 + agrp * 4 + reg];
      mn[rt][reg] = -INFINITY;
    }

  const int ITERS = NC / 16;             // 16 tiles, even
  const unsigned short* bp = xb + (size_t)(c0 + cg) * D + agrp * 8;
  const int* tp = tg + c0 + cg;

  short8 b0[4], b1[4];
  int tc0, tc1;
#pragma unroll
  for (int kk = 0; kk < 4; ++kk)
    b0[kk] = *reinterpret_cast<const short8*>(bp + kk * 32);
  tc0 = *tp;

  for (int i = 0; i < ITERS; i += 2) {
#pragma unroll
    for (int kk = 0; kk < 4; ++kk)
      b1[kk] = *reinterpret_cast<const short8*>(bp + 16 * D + kk * 32);
    tc1 = tp[16];
#pragma unroll
    for (int rt = 0; rt < 4; ++rt) {
      f32x4 acc = {0.f, 0.f, 0.f, 0.f};
#pragma unroll
      for (int kk = 0; kk < 4; ++kk)
        acc = __builtin_amdgcn_mfma_f32_16x16x32_bf16(a[rt][kk], b0[kk], acc, 0, 0, 0);
#pragma unroll
      for (int reg = 0; reg < 4; ++reg)
        mn[rt][reg] = fmaxf(mn[rt][reg], (tc0 == trow[rt][reg]) ? -INFINITY : acc[reg]);
    }
    bool more = (i + 2 < ITERS);
    const unsigned short* bp2 = more ? bp + 32 * D : bp;
    const int* tp2 = more ? tp + 32 : tp;
#pragma unroll
    for (int kk = 0; kk < 4; ++kk)
      b0[kk] = *reinterpret_cast<const short8*>(bp2 + kk * 32);
    tc0 = *tp2;
#pragma unroll
    for (int rt = 0; rt < 4; ++rt) {
      f32x4 acc = {0.f, 0.f, 0.f, 0.f};
#pragma unroll
      for (int kk = 0; kk < 4; ++kk)
        acc = __builtin_amdgcn_mfma_f32_16x16x32_bf16(a[rt][kk], b1[kk], acc, 0, 0, 0);
#pragma unroll
      for (int reg = 0; reg < 4; ++reg)
        mn[rt][reg] = fmaxf(mn[rt][reg], (tc1 == trow[rt][reg]) ? -INFINITY : acc[reg]);
    }
    bp = bp2; tp = tp2;
  }

  // reduce across the 16 cg-lanes within each agrp group
#pragma unroll
  for (int m = 1; m < 16; m <<= 1)
#pragma unroll
    for (int rt = 0; rt < 4; ++rt)
#pragma unroll
      for (int reg = 0; reg < 4; ++reg)
        mn[rt][reg] = fmaxf(mn[rt][reg], __shfl_xor(mn[rt][reg], m, 16));

  if (cg == 0) {
#pragma unroll
    for (int rt = 0; rt < 4; ++rt)
#pragma unroll
      for (int reg = 0; reg < 4; ++reg)
        atomicMax(&mn_u[r0 + rt * 16 + agrp * 4 + reg], fkey(mn[rt][reg]));
  }
}

// Positives: tiny per-row f32 kernel over class lists. One wave per row.
// Computes max_pos, pos_loss (needs thp = max_neg + margin), writes thn[] for pass2.
__launch_bounds__(256)
__global__ void k_pos(const float* __restrict__ x, const int* __restrict__ tg,
                      const unsigned* __restrict__ mn_u,
                      const int* __restrict__ cls_cnt, const int* __restrict__ cls_idx,
                      float* __restrict__ thn, float* __restrict__ pos_part, int n) {
  int lane = threadIdx.x & 63, wid = threadIdx.x >> 6;
  int r = blockIdx.x * 4 + wid;
  int tr = tg[r];
  float2 xr = *reinterpret_cast<const float2*>(x + (size_t)r * D + lane * 2);
  float mneg = fdec(mn_u[r]);
  float thp = mneg + MARGIN;
  int cnt = cls_cnt[tr];
  int m = cnt < MAXC ? cnt : MAXC;
  float mpos = -INFINITY, pl = 0.f;
  for (int k = 0; k < m; ++k) {
    int j = cls_idx[tr * MAXC + k];
    if (j == r) continue;
    float2 xj = *reinterpret_cast<const float2*>(x + (size_t)j * D + lane * 2);
    float d = xr.x * xj.x + xr.y * xj.y;
#pragma unroll
    for (int mm = 1; mm < 64; mm <<= 1) d += __shfl_xor(d, mm, 64);
    mpos = fmaxf(mpos, d);
    if (d < thp) pl += 1.0f - d;
  }
  bool has_pos = cnt > 1;
  if (lane == 0) thn[r] = has_pos ? (fmaxf(0.6f, mpos) - MARGIN) : INFINITY;
  __shared__ float red[4];
  if (lane == 0) red[wid] = has_pos ? pl : 0.f;
  __syncthreads();
  if (threadIdx.x == 0)
    pos_part[blockIdx.x] = red[0] + red[1] + red[2] + red[3];
}

// Pass 2: negative-loss sums, thresholds precomputed per row in thn[].
__launch_bounds__(64, 3)
__global__ void k_pass2(const unsigned short* __restrict__ xb, const int* __restrict__ tg,
                        const float* __restrict__ thn, float* __restrict__ loss_part, int n) {
  const int lane = threadIdx.x;
  const int nstrips = n / BM;
  const int strip = blockIdx.x % nstrips;
  const int cgrp  = blockIdx.x / nstrips;
  const int r0 = strip * BM;
  const int NC = n / NCG;
  const int c0 = cgrp * NC;
  const int cg = lane & 15;
  const int agrp = lane >> 4;

  short8 a[4][4];
#pragma unroll
  for (int rt = 0; rt < 4; ++rt)
#pragma unroll
    for (int kk = 0; kk < 4; ++kk)
      a[rt][kk] = *reinterpret_cast<const short8*>(
          xb + (size_t)(r0 + rt * 16 + cg) * D + kk * 32 + agrp * 8);

  int trow[4][4];
  float th[4][4];
#pragma unroll
  for (int rt = 0; rt < 4; ++rt) {
    float4 t4 = *reinterpret_cast<const float4*>(thn + r0 + rt * 16 + agrp * 4);
    th[rt][0] = t4.x; th[rt][1] = t4.y; th[rt][2] = t4.z; th[rt][3] = t4.w;
#pragma unroll
    for (int reg = 0; reg < 4; ++reg)
      trow[rt][reg] = tg[r0 + rt * 16 + agrp * 4 + reg];
  }

  float ls[4] = {0.f, 0.f, 0.f, 0.f};

  const int ITERS = NC / 16;
  const unsigned short* bp = xb + (size_t)(c0 + cg) * D + agrp * 8;
  const int* tp = tg + c0 + cg;

  short8 b0[4], b1[4];
  int tc0, tc1;
#pragma unroll
  for (int kk = 0; kk < 4; ++kk)
    b0[kk] = *reinterpret_cast<const short8*>(bp + kk * 32);
  tc0 = *tp;

  for (int i = 0; i < ITERS; i += 2) {
#pragma unroll
    for (int kk = 0; kk < 4; ++kk)
      b1[kk] = *reinterpret_cast<const short8*>(bp + 16 * D + kk * 32);
    tc1 = tp[16];
#pragma unroll
    for (int rt = 0; rt < 4; ++rt) {
      f32x4 acc = {0.f, 0.f, 0.f, 0.f};
#pragma unroll
      for (int kk = 0; kk < 4; ++kk)
        acc = __builtin_amdgcn_mfma_f32_16x16x32_bf16(a[rt][kk], b0[kk], acc, 0, 0, 0);
#pragma unroll
      for (int reg = 0; reg < 4; ++reg) {
        float s = acc[reg];
        ls[reg] += ((tc0 != trow[rt][reg]) && (s > th[rt][reg])) ? s : 0.f;
      }
    }
    bool more = (i + 2 < ITERS);
    const unsigned short* bp2 = more ? bp + 32 * D : bp;
    const int* tp2 = more ? tp + 32 : tp;
#pragma unroll
    for (int kk = 0; kk < 4; ++kk)
      b0[kk] = *reinterpret_cast<const short8*>(bp2 + kk * 32);
    tc0 = *tp2;
#pragma unroll
    for (int rt = 0; rt < 4; ++rt) {
      f32x4 acc = {0.f, 0.f, 0.f, 0.f};
#pragma unroll
      for (int kk = 0; kk < 4; ++kk)
        acc = __builtin_amdgcn_mfma_f32_16x16x32_bf16(a[rt][kk], b1[kk], acc, 0, 0, 0);
#pragma unroll
      for (int reg = 0; reg < 4; ++reg) {
        float s = acc[reg];
        ls[reg] += ((tc1 != trow[rt][reg]) && (s > th[rt][reg])) ? s : 0.f;
      }
    }
    bp = bp2; tp = tp2;
  }

  float tot = ls[0] + ls[1] + ls[2] + ls[3];
#pragma unroll
  for (int m = 1; m < 64; m <<= 1) tot += __shfl_xor(tot, m, 64);
  if (lane == 0) loss_part[blockIdx.x] = tot;
}

// Diagnostics on the last row, pure f32.
__global__ void k_diag(const float* __restrict__ x, const int* __restrict__ tg,
                       float* __restrict__ dpart, int n) {
  int col = blockIdx.x * blockDim.x + threadIdx.x;
  int R = n - 1;
  int tR = tg[R];
  const float4* xr = reinterpret_cast<const float4*>(x + (size_t)R * D);
  const float4* xc = reinterpret_cast<const float4*>(x + (size_t)col * D);
  float dot = 0.f;
#pragma unroll
  for (int k = 0; k < D / 4; ++k) {
    float4 va = xr[k], vb = xc[k];
    dot += va.x * vb.x + va.y * vb.y + va.z * vb.z + va.w * vb.w;
  }
  int t = tg[col];
  bool same = (t == tR);
  bool isR = (col == R);
  float v[4];
  v[0] = (same && !isR) ? dot : 0.f;
  v[1] = (same && !isR) ? 1.f : 0.f;
  v[2] = (!same) ? dot : 0.f;
  v[3] = (!same) ? 1.f : 0.f;
  int lane = threadIdx.x & 63, wid = threadIdx.x >> 6;
#pragma unroll
  for (int m = 1; m < 64; m <<= 1)
#pragma unroll
    for (int j = 0; j < 4; ++j) v[j] += __shfl_xor(v[j], m, 64);
  __shared__ float red[4][4];
  if (lane == 0) {
#pragma unroll
    for (int j = 0; j < 4; ++j) red[wid][j] = v[j];
  }
  __syncthreads();
  if (threadIdx.x == 0) {
#pragma unroll
    for (int j = 0; j < 4; ++j)
      dpart[blockIdx.x * 4 + j] = red[0][j] + red[1][j] + red[2][j] + red[3][j];
  }
}

__global__ void k_final(const float* __restrict__ loss_part, int nlp,
                        const float* __restrict__ pos_part, int npp,
                        const float* __restrict__ dpart, int ndiag,
                        float* __restrict__ out, int n) {
  float s = 0.f;
  for (int i = threadIdx.x; i < nlp; i += 256) s += loss_part[i];
  for (int i = threadIdx.x; i < npp; i += 256) s += pos_part[i];
  int lane = threadIdx.x & 63, wid = threadIdx.x >> 6;
#pragma unroll
  for (int m = 1; m < 64; m <<= 1) s += __shfl_xor(s, m, 64);
  __shared__ float red[4];
  if (lane == 0) red[wid] = s;
  __syncthreads();
  if (threadIdx.x == 0) {
    float loss = red[0] + red[1] + red[2] + red[3];
    float ps = 0.f, pc = 0.f, ns = 0.f, nc = 0.f;
    for (int b = 0; b < ndiag; ++b) {
      ps += dpart[b * 4 + 0];
      pc += dpart[b * 4 + 1];
      ns += dpart[b * 4 + 2];
      nc += dpart[b * 4 + 3];
    }
    out[0] = loss / (float)n;
    out[1] = 0.f;
    out[2] = 0.f;
    out[3] = 0.f;
    out[4] = ps / fmaxf(pc, 1.f);
    out[5] = ns / fmaxf(nc, 1.f);
  }
}

extern "C" void kernel_launch(void* const* d_in, const int* in_sizes, int n_in,
                              void* d_out, int out_size, void* d_ws, size_t ws_size,
                              hipStream_t stream) {
  const float* x = (const float*)d_in[0];
  const int* tg = (const int*)d_in[1];
  float* out = (float*)d_out;
  int n = in_sizes[1];  // 8192

  char* ws = (char*)d_ws;
  unsigned short* xb = (unsigned short*)ws;                     // n*D bf16 = 2 MB
  size_t off = (size_t)n * D * 2;
  unsigned* mn_u = (unsigned*)(ws + off); off += (size_t)n * 4;
  float* thn = (float*)(ws + off); off += (size_t)n * 4;
  int* cls_cnt = (int*)(ws + off); off += 512 * 4;
  int* cls_idx = (int*)(ws + off); off += 512 * MAXC * 4;
  int nb = (n / BM) * NCG;                                      // 4096
  float* loss_part = (float*)(ws + off); off += (size_t)nb * 4;
  float* pos_part = (float*)(ws + off); off += (size_t)(n / 4) * 4;
  float* dpart = (float*)(ws + off);                            // (n/256)*4 f32

  int total = n * D;
  k_convert<<<total / 1024, 256, 0, stream>>>(x, xb, total);
  k_zero<<<(n + 255) / 256, 256, 0, stream>>>(cls_cnt, mn_u, n);
  k_fill<<<(n + 255) / 256, 256, 0, stream>>>(tg, cls_cnt, cls_idx, n);
  k_pass1<<<nb, 64, 0, stream>>>(xb, tg, mn_u, n);
  k_pos<<<n / 4, 256, 0, stream>>>(x, tg, mn_u, cls_cnt, cls_idx, thn, pos_part, n);
  k_pass2<<<nb, 64, 0, stream>>>(xb, tg, thn, loss_part, n);
  int ndiag = n / 256;
  k_diag<<<ndiag, 256, 0, stream>>>(x, tg, dpart, n);
  k_final<<<1, 256, 0, stream>>>(loss_part, nb, pos_part, n / 4, dpart, ndiag, out, n);
}